// Round 3
// baseline (10438.408 us; speedup 1.0000x reference)
//
#include <hip/hip_runtime.h>
#include <hip/hip_bf16.h>
#include <stdint.h>

#define NB 2
#define NT 8
#define NN 50000
#define NF 32
#define NH_ 64
#define NE_ 800000
#define NBLK 512
#define NTHR 512
#define NWAVE (NBLK * 8)          // 4096 waves
#define NTILE ((NB * NN) / 16)    // 6250 step tiles
#define NCHUNK ((NN + 127) / 128) // 391 scan chunks

typedef __hip_bfloat16 bf16;
typedef _Float16 h16;
typedef __attribute__((ext_vector_type(2))) _Float16 f16x2;
typedef __attribute__((ext_vector_type(4))) _Float16 f16x4;
typedef __attribute__((ext_vector_type(4))) float f32x4;

__device__ __forceinline__ float b2f(bf16 x) { return __bfloat162float(x); }
__device__ __forceinline__ bf16 f2b(float x) { return __float2bfloat16(x); }
__device__ __forceinline__ float bu2f(unsigned short u) {
    return __uint_as_float(((unsigned)u) << 16);
}
__device__ __forceinline__ unsigned short f2bu(float f) {
    return __builtin_bit_cast(unsigned short, f2b(f));
}
__device__ __forceinline__ float ldx(const void* p, size_t i, int fp32) {
    return fp32 ? ((const float*)p)[i] : b2f(((const bf16*)p)[i]);
}

struct KParams {
    const void* x_in; const int* esrc; const int* edst; const void* efeat; const void* initH;
    const void* A; const void* Bm; const void* C; const void* D; const void* Fm; const void* G;
    const void* W1; const void* b1; const void* W2; const void* b2; const void* W3; const void* b3;
    int* cnt; int* partials; int2* pairs; h16* H; h16* agg; void* out; int* bar;
};

// Grid barrier: all 512 blocks are co-resident by construction
// (2 blocks/CU via 64.4KB LDS, VGPR<=128 via launch_bounds). Device-scope
// release/acquire; monotonic phase counter (no reset).
__device__ __forceinline__ void gsync(int* bar, int expect) {
    __threadfence();   // release my writes device-wide
    __syncthreads();
    if (threadIdx.x == 0) {
        __hip_atomic_fetch_add(bar, 1, __ATOMIC_RELEASE, __HIP_MEMORY_SCOPE_AGENT);
        while (__hip_atomic_load(bar, __ATOMIC_ACQUIRE, __HIP_MEMORY_SCOPE_AGENT) < expect)
            __builtin_amdgcn_s_sleep(2);
    }
    __syncthreads();
    __threadfence();   // acquire: see everyone else's writes
}

// ---------------- aggregation phase (CSR gather, 8 gathers in flight) ----------------
template <int FP32>
__device__ __forceinline__ void agg_phase(
    const uint32_t* __restrict__ H2, const int* __restrict__ cend,
    const int2* __restrict__ pairs, const void* __restrict__ efeat, int te,
    uint32_t* __restrict__ agg2, int gwave) {
    int lane = threadIdx.x & 63;
    size_t efoff = ((size_t)(lane >> 5) * NT + te) * NE_;
    const float* ef32 = (const float*)efeat + efoff;
    const bf16* ef16 = (const bf16*)efeat + efoff;
    for (int n0 = gwave; n0 < NN; n0 += NWAVE) {
        int n = __builtin_amdgcn_readfirstlane(n0);
        int j0 = (n == 0) ? 0 : cend[n - 1];
        int j1 = cend[n];
        float acc0 = 0.f, acc1 = 0.f;
        int j = j0;
        for (; j + 7 < j1; j += 8) {
            float e[8]; uint32_t h[8];
#pragma unroll
            for (int q = 0; q < 8; ++q) {
                int2 p = pairs[j + q];
                h[q] = H2[(size_t)p.x * 64 + lane];
                e[q] = FP32 ? ef32[p.y] : b2f(ef16[p.y]);
            }
#pragma unroll
            for (int q = 0; q < 8; ++q) {
                f16x2 v = __builtin_bit_cast(f16x2, h[q]);
                acc0 = fmaf(e[q], (float)v[0], acc0);
                acc1 = fmaf(e[q], (float)v[1], acc1);
            }
        }
        for (; j < j1; ++j) {
            int2 p = pairs[j];
            uint32_t hq = H2[(size_t)p.x * 64 + lane];
            float eq = FP32 ? ef32[p.y] : b2f(ef16[p.y]);
            f16x2 v = __builtin_bit_cast(f16x2, hq);
            acc0 = fmaf(eq, (float)v[0], acc0);
            acc1 = fmaf(eq, (float)v[1], acc1);
        }
        f16x2 o; o[0] = (h16)acc0; o[1] = (h16)acc1;
        agg2[(size_t)n * 64 + lane] = __builtin_bit_cast(uint32_t, o);
    }
}

// ---------------- fused step phase: pre + tanh + H update + MLP + out ----------------
template <int FP32>
__device__ __forceinline__ void step_phase(
    const f16x4* __restrict__ FR, const float4* __restrict__ BI,
    const void* __restrict__ x_in, void* __restrict__ out, int t,
    const h16* __restrict__ agg, h16* __restrict__ H, int gwave) {
    int lane = threadIdx.x & 63, m = lane & 15, g = lane >> 4;
    for (int wt = gwave; wt < NTILE; wt += NWAVE) {
        int r = wt * 16 + m;   // batch-interleaved row id (r = n*2 + b)
        int b = r & 1;
        int n = r >> 1;

        const f16x4* Hp = (const f16x4*)(H + (size_t)r * NH_);
        const f16x4* Ap = (const f16x4*)(agg + (size_t)r * NH_);
        f16x4 hf[4], af[4], xf[2];
#pragma unroll
        for (int ks = 0; ks < 4; ++ks) hf[ks] = Hp[ks * 4 + g];
#pragma unroll
        for (int ks = 0; ks < 4; ++ks) af[ks] = Ap[ks * 4 + g];

        size_t xbase = (t < NT) ? (((size_t)b * NT + t) * NN + (size_t)n) * NF
                                : (((size_t)b * (NT + 1) + (NT - 1)) * NN + (size_t)n) * NF;
        const void* xp = (t < NT) ? x_in : (const void*)out;
        if (FP32) {
            const float4* Xp = (const float4*)((const float*)xp + xbase);
#pragma unroll
            for (int ksl = 0; ksl < 2; ++ksl) {
                float4 xv = Xp[ksl * 4 + g];
                f16x4 h; h[0] = (h16)xv.x; h[1] = (h16)xv.y; h[2] = (h16)xv.z; h[3] = (h16)xv.w;
                xf[ksl] = h;
            }
        } else {
            const ushort4* Xp = (const ushort4*)((const bf16*)xp + xbase);
#pragma unroll
            for (int ksl = 0; ksl < 2; ++ksl) {
                ushort4 xv = Xp[ksl * 4 + g];
                f16x4 h; h[0] = (h16)bu2f(xv.x); h[1] = (h16)bu2f(xv.y);
                h[2] = (h16)bu2f(xv.z); h[3] = (h16)bu2f(xv.w);
                xf[ksl] = h;
            }
        }

        // pre = [H|x|agg] @ [A|Bm|C]^T + D  (hi + lo*2^-11 split weights)
        f32x4 acc[4], accl[4];
#pragma unroll
        for (int ot = 0; ot < 4; ++ot) {
            float4 bv = BI[ot * 4 + g];
            acc[ot]  = f32x4{bv.x, bv.y, bv.z, bv.w};
            accl[ot] = f32x4{0.f, 0.f, 0.f, 0.f};
        }
#pragma unroll
        for (int ks = 0; ks < 10; ++ks) {
            f16x4 bfr = (ks < 4) ? hf[ks] : ((ks < 6) ? xf[ks - 4] : af[ks - 6]);
#pragma unroll
            for (int ot = 0; ot < 4; ++ot) {
                acc[ot] = __builtin_amdgcn_mfma_f32_16x16x16f16(
                    FR[(ot * 10 + ks) * 64 + lane], bfr, acc[ot], 0, 0, 0);
                accl[ot] = __builtin_amdgcn_mfma_f32_16x16x16f16(
                    FR[(40 + ot * 10 + ks) * 64 + lane], bfr, accl[ot], 0, 0, 0);
            }
        }

        // H_new = H + tanh(pre)
        f16x4 hnf[4];
        f16x4* Hw = (f16x4*)(H + (size_t)r * NH_);
#pragma unroll
        for (int ot = 0; ot < 4; ++ot) {
            f16x4 hn;
#pragma unroll
            for (int j = 0; j < 4; ++j) {
                float pre = acc[ot][j] + accl[ot][j] * (1.f / 2048.f);
                hn[j] = (h16)((float)hf[ot][j] + tanhf(pre));
            }
            hnf[ot] = hn;
            Hw[ot * 4 + g] = hn;
        }

        // h1 = relu(Hn @ W1^T + b1)
        f32x4 a1[4];
#pragma unroll
        for (int ot = 0; ot < 4; ++ot) {
            float4 bv = BI[16 + ot * 4 + g];
            a1[ot] = f32x4{bv.x, bv.y, bv.z, bv.w};
        }
#pragma unroll
        for (int ks = 0; ks < 4; ++ks)
#pragma unroll
            for (int ot = 0; ot < 4; ++ot)
                a1[ot] = __builtin_amdgcn_mfma_f32_16x16x16f16(
                    FR[(80 + ot * 4 + ks) * 64 + lane], hnf[ks], a1[ot], 0, 0, 0);
        f16x4 h1f[4];
#pragma unroll
        for (int ot = 0; ot < 4; ++ot) {
            f16x4 h;
#pragma unroll
            for (int j = 0; j < 4; ++j) h[j] = (h16)fmaxf(a1[ot][j], 0.f);
            h1f[ot] = h;
        }

        // h2 = relu(h1 @ W2^T + b2)
        f32x4 a2[4];
#pragma unroll
        for (int ot = 0; ot < 4; ++ot) {
            float4 bv = BI[32 + ot * 4 + g];
            a2[ot] = f32x4{bv.x, bv.y, bv.z, bv.w};
        }
#pragma unroll
        for (int ks = 0; ks < 4; ++ks)
#pragma unroll
            for (int ot = 0; ot < 4; ++ot)
                a2[ot] = __builtin_amdgcn_mfma_f32_16x16x16f16(
                    FR[(96 + ot * 4 + ks) * 64 + lane], h1f[ks], a2[ot], 0, 0, 0);
        f16x4 h2f4[4];
#pragma unroll
        for (int ot = 0; ot < 4; ++ot) {
            f16x4 h;
#pragma unroll
            for (int j = 0; j < 4; ++j) h[j] = (h16)fmaxf(a2[ot][j], 0.f);
            h2f4[ot] = h;
        }

        // y = h2 @ W3^T + x @ Fm^T + (b3 + G)
        f32x4 ay[2];
#pragma unroll
        for (int ot = 0; ot < 2; ++ot) {
            float4 bv = BI[48 + ot * 4 + g];
            ay[ot] = f32x4{bv.x, bv.y, bv.z, bv.w};
        }
#pragma unroll
        for (int ks = 0; ks < 6; ++ks) {
            f16x4 bfr = (ks < 4) ? h2f4[ks] : xf[ks - 4];
#pragma unroll
            for (int ot = 0; ot < 2; ++ot)
                ay[ot] = __builtin_amdgcn_mfma_f32_16x16x16f16(
                    FR[(112 + ot * 6 + ks) * 64 + lane], bfr, ay[ot], 0, 0, 0);
        }

        size_t obase = (((size_t)b * (NT + 1) + t) * NN + (size_t)n) * NF;
        if (FP32) {
            float4* Op = (float4*)((float*)out + obase);
#pragma unroll
            for (int ot = 0; ot < 2; ++ot)
                Op[ot * 4 + g] = make_float4(ay[ot][0], ay[ot][1], ay[ot][2], ay[ot][3]);
        } else {
            ushort4* Op = (ushort4*)((bf16*)out + obase);
#pragma unroll
            for (int ot = 0; ot < 2; ++ot) {
                ushort4 u;
                u.x = f2bu(ay[ot][0]); u.y = f2bu(ay[ot][1]);
                u.z = f2bu(ay[ot][2]); u.w = f2bu(ay[ot][3]);
                Op[ot * 4 + g] = u;
            }
        }
    }
}

// ---------------- the single persistent kernel ----------------
__global__ __launch_bounds__(NTHR, 4) void k_run(KParams P) {
    __shared__ float4 lds4[4024];  // 64384B: 124 frags * 512 + 896B bias (aliased by scan)
    __shared__ int sh_found;
    int tid = threadIdx.x;
    int bid = blockIdx.x;
    int gtid = bid * NTHR + tid;
    const int GT = NBLK * NTHR;
    int gwave = bid * 8 + (tid >> 6);
    int ph = 0;

    // --- dtype detect (per block, no sync needed) ---
    if (tid == 0) sh_found = 0;
    __syncthreads();
    {
        const uint32_t* xw = (const uint32_t*)P.x_in;
        int hit = 0;
        for (int i = tid; i < 4096; i += NTHR) {
            uint32_t ex = ((xw[i] & 0xFFFFu) >> 7) & 0xFFu;
            if (ex >= 0xC1u) hit = 1;
        }
        if (hit) sh_found = 1;  // benign race
        __syncthreads();
    }
    int fp32v = sh_found;

    // --- P1: zero cnt/partials, init H ---
    for (int i = gtid; i < NN; i += GT) P.cnt[i] = 0;
    if (gtid < NBLK) P.partials[gtid] = 0;
    {
        uint32_t* H2w = (uint32_t*)P.H;
        for (int i = gtid; i < NB * NN * 32; i += GT) {
            int d0 = (i & 31) * 2;
            f16x2 hv;
            hv[0] = (h16)ldx(P.initH, d0, fp32v);
            hv[1] = (h16)ldx(P.initH, d0 + 1, fp32v);
            H2w[i] = __builtin_bit_cast(uint32_t, hv);
        }
    }
    ++ph; gsync(P.bar, NBLK * ph);

    // --- P2: degree histogram ---
    for (int e = gtid; e < NE_; e += GT) atomicAdd(&P.cnt[P.edst[e]], 1);
    ++ph; gsync(P.bar, NBLK * ph);

    // --- P3: per-chunk exclusive scan (chunk=128), partial totals ---
    {
        int* si = (int*)lds4;
        if (bid < NCHUNK) {
            int base = bid * 128;
            int v = 0;
            if (tid < 128 && base + tid < NN) v = P.cnt[base + tid];
            if (tid < 128) si[tid] = v;
            __syncthreads();
            for (int off = 1; off < 128; off <<= 1) {
                int a = (tid >= off && tid < 128) ? si[tid - off] : 0;
                __syncthreads();
                if (tid < 128) si[tid] += a;
                __syncthreads();
            }
            if (tid < 128 && base + tid < NN) P.cnt[base + tid] = si[tid] - v;
            if (tid == 127) P.partials[bid] = si[127];
        }
    }
    ++ph; gsync(P.bar, NBLK * ph);

    // --- P4: top scan of 512 partials (block 0) ---
    if (bid == 0) {
        int* si = (int*)lds4;
        int v = P.partials[tid];
        si[tid] = v;
        __syncthreads();
        for (int off = 1; off < NTHR; off <<= 1) {
            int a = (tid >= off) ? si[tid - off] : 0;
            __syncthreads();
            si[tid] += a;
            __syncthreads();
        }
        P.partials[tid] = si[tid] - v;  // exclusive
    }
    ++ph; gsync(P.bar, NBLK * ph);

    // --- P5: apply chunk offsets -> cnt = start offsets ---
    for (int i = gtid; i < NN; i += GT) P.cnt[i] += P.partials[i >> 7];
    ++ph; gsync(P.bar, NBLK * ph);

    // --- P6: CSR fill (cursors -> ends); pairs = (src, eid) ---
    for (int e = gtid; e < NE_; e += GT) {
        int s = P.esrc[e];
        int pos = atomicAdd(&P.cnt[P.edst[e]], 1);
        P.pairs[pos] = make_int2(s, e);
    }
    ++ph; gsync(P.bar, NBLK * ph);

    // --- weight fragpack straight into LDS (per block, once for all steps) ---
    {
        f16x4* FRw = (f16x4*)lds4;
        float* BIw = (float*)lds4 + 15872;
        for (int idx = tid; idx < 8160; idx += NTHR) {
            if (idx < 7936) {
                int frag = idx >> 6, l = idx & 63;
                int mr = l & 15, g2 = l >> 4;
                int pre = frag < 80;
                int q, ot, ks;
                if (pre)             { q = (frag < 40) ? frag : frag - 40; ot = q / 10; ks = q % 10; }
                else if (frag < 96)  { q = frag - 80;  ot = q >> 2; ks = q & 3; }
                else if (frag < 112) { q = frag - 96;  ot = q >> 2; ks = q & 3; }
                else                 { q = frag - 112; ot = q / 6;  ks = q % 6; }
                int row = ot * 16 + mr;
                f16x4 outv;
#pragma unroll
                for (int i = 0; i < 4; ++i) {
                    int k = ks * 16 + g2 * 4 + i;
                    if (pre) {
                        float v;
                        if (k < 64)      v = ldx(P.A,  (size_t)row * 64 + k, fp32v);
                        else if (k < 96) v = ldx(P.Bm, (size_t)row * 32 + (k - 64), fp32v);
                        else             v = ldx(P.C,  (size_t)row * 64 + (k - 96), fp32v);
                        h16 hi = (h16)v;
                        outv[i] = (frag < 40) ? hi : (h16)((v - (float)hi) * 2048.f);
                    } else if (frag < 96) {
                        outv[i] = (h16)ldx(P.W1, (size_t)row * 64 + k, fp32v);
                    } else if (frag < 112) {
                        outv[i] = (h16)ldx(P.W2, (size_t)row * 64 + k, fp32v);
                    } else {
                        float v = (k < 64) ? ldx(P.W3, (size_t)row * 64 + k, fp32v)
                                           : ldx(P.Fm, (size_t)row * 32 + (k - 64), fp32v);
                        outv[i] = (h16)v;
                    }
                }
                FRw[(size_t)frag * 64 + l] = outv;
            } else {
                int j = idx - 7936;
                float v;
                if      (j < 64)  v = ldx(P.D,  j,       fp32v);
                else if (j < 128) v = ldx(P.b1, j - 64,  fp32v);
                else if (j < 192) v = ldx(P.b2, j - 128, fp32v);
                else              v = ldx(P.b3, j - 192, fp32v) + ldx(P.G, j - 192, fp32v);
                BIw[j] = v;
            }
        }
        __syncthreads();
    }

    const f16x4* FR = (const f16x4*)lds4;
    const float4* BI = (const float4*)((const float*)lds4 + 15872);

    // --- time loop: aggregate | barrier | step | barrier ---
    for (int t = 0; t <= NT; ++t) {
        int te = (t < NT) ? t : (NT - 1);
        if (fp32v)
            agg_phase<1>((const uint32_t*)P.H, P.cnt, P.pairs, P.efeat, te,
                         (uint32_t*)P.agg, gwave);
        else
            agg_phase<0>((const uint32_t*)P.H, P.cnt, P.pairs, P.efeat, te,
                         (uint32_t*)P.agg, gwave);
        ++ph; gsync(P.bar, NBLK * ph);
        if (fp32v)
            step_phase<1>(FR, BI, P.x_in, P.out, t, P.agg, P.H, gwave);
        else
            step_phase<0>(FR, BI, P.x_in, P.out, t, P.agg, P.H, gwave);
        ++ph; gsync(P.bar, NBLK * ph);
    }
}

// ---------------- ws-too-small diagnostic ----------------
__global__ void k_diag(float* __restrict__ o, int nwords, float V) {
    int i = blockIdx.x * 256 + threadIdx.x;
    if (i < nwords) o[i] = V;
}

// ---------------- host ----------------

extern "C" void kernel_launch(void* const* d_in, const int* in_sizes, int n_in,
                              void* d_out, int out_size, void* d_ws, size_t ws_size,
                              hipStream_t stream) {
    // workspace layout (~30.8 MiB)
    int*  bar      = (int*)d_ws;                       // 64 B reserved
    int*  cnt      = (int*)((char*)d_ws + 64);         // NN
    int*  partials = cnt + NN;                         // 512
    int2* pairs    = (int2*)(partials + NBLK);         // NE (src, eid)
    h16*  H        = (h16*)(pairs + NE_);              // NB*NN*64 (r' = n*2+b)
    h16*  agg      = H + (size_t)NB * NN * NH_;        // NB*NN*64

    size_t needed = 64 + (size_t)NN * 4 + (size_t)NBLK * 4 + (size_t)NE_ * 8
                  + (size_t)NB * NN * NH_ * 2 * 2;
    if (ws_size < needed) {
        unsigned k = (unsigned)(ws_size >> 20); if (k > 255) k = 255;
        float V = 16.f * (float)(k + 1);
        int nw = out_size / 2;
        k_diag<<<(nw + 255) / 256, 256, 0, stream>>>((float*)d_out, nw, V);
        return;
    }

    hipMemsetAsync(bar, 0, 4, stream);  // barrier counter must start at 0 every replay

    KParams hp;
    hp.x_in = d_in[0]; hp.esrc = (const int*)d_in[1]; hp.edst = (const int*)d_in[2];
    hp.efeat = d_in[3]; hp.initH = d_in[4];
    hp.A = d_in[5]; hp.Bm = d_in[6]; hp.C = d_in[7]; hp.D = d_in[8];
    hp.Fm = d_in[9]; hp.G = d_in[10]; hp.W1 = d_in[11]; hp.b1 = d_in[12];
    hp.W2 = d_in[13]; hp.b2 = d_in[14]; hp.W3 = d_in[15]; hp.b3 = d_in[16];
    hp.cnt = cnt; hp.partials = partials; hp.pairs = pairs;
    hp.H = H; hp.agg = agg; hp.out = d_out; hp.bar = bar;

    k_run<<<dim3(NBLK), dim3(NTHR), 0, stream>>>(hp);
}

// Round 4
// 1009.814 us; speedup vs baseline: 10.3370x; 10.3370x over previous
//
#include <hip/hip_runtime.h>
#include <hip/hip_bf16.h>
#include <stdint.h>

#define NB 2
#define NT 8
#define NN 50000
#define NF 32
#define NH_ 64
#define NE_ 800000

typedef __hip_bfloat16 bf16;
typedef _Float16 h16;
typedef __attribute__((ext_vector_type(2))) _Float16 f16x2;
typedef __attribute__((ext_vector_type(4))) _Float16 f16x4;
typedef __attribute__((ext_vector_type(4))) float f32x4;

__device__ __forceinline__ float b2f(bf16 x) { return __bfloat162float(x); }
__device__ __forceinline__ bf16 f2b(float x) { return __float2bfloat16(x); }
__device__ __forceinline__ float bu2f(unsigned short u) {
    return __uint_as_float(((unsigned)u) << 16);
}
__device__ __forceinline__ unsigned short f2bu(float f) {
    return __builtin_bit_cast(unsigned short, f2b(f));
}
__device__ __forceinline__ float ldx(const void* p, size_t i, int fp32) {
    return fp32 ? ((const float*)p)[i] : b2f(((const bf16*)p)[i]);
}

// ---------------- dtype detector ----------------
__global__ void k_detect(const uint32_t* __restrict__ xw, int* __restrict__ flag) {
    __shared__ int found;
    if (threadIdx.x == 0) found = 0;
    __syncthreads();
    int hit = 0;
    for (int i = threadIdx.x; i < 4096; i += 256) {
        uint32_t lo = xw[i] & 0xFFFFu;
        uint32_t ex = (lo >> 7) & 0xFFu;
        if (ex >= 0xC1u) hit = 1;
    }
    if (hit) found = 1;  // benign race: all writers store 1
    __syncthreads();
    if (threadIdx.x == 0) flag[0] = found;
}

// ---------------- weight fragment packing ----------------
// frag f at byte f*512, lane l at +l*8 holds 4 f16 = A-fragment of
// v_mfma_f32_16x16x16_f16: W[ot*16 + (l&15)][ks*16 + (l>>4)*4 + i].
// [0,39] pre-hi (ot*10+ks over [A|Bm|C], K=160), [40,79] pre-lo (*2^11),
// [80,95] W1, [96,111] W2, [112,123] y=[W3|Fm] (ot*6+ks, K=96).
// bias block at byte 63488: D[64] b1[64] b2[64] (b3+G)[32] fp32.
__global__ void k_fragpack(const void* A, const void* Bm, const void* C, const void* D,
                           const void* Fm, const void* G, const void* W1, const void* b1,
                           const void* W2, const void* b2, const void* W3, const void* b3,
                           const int* __restrict__ flag, float* __restrict__ img) {
    int fp32 = flag[0];
    int idx = blockIdx.x * 256 + threadIdx.x;
    if (idx < 7936) {
        int frag = idx >> 6, l = idx & 63;
        int mr = l & 15, g = l >> 4;
        int pre = frag < 80;
        int q, ot, ks;
        if (pre)             { q = (frag < 40) ? frag : frag - 40; ot = q / 10; ks = q % 10; }
        else if (frag < 96)  { q = frag - 80;  ot = q >> 2; ks = q & 3; }
        else if (frag < 112) { q = frag - 96;  ot = q >> 2; ks = q & 3; }
        else                 { q = frag - 112; ot = q / 6;  ks = q % 6; }
        int row = ot * 16 + mr;
        f16x4 outv;
#pragma unroll
        for (int i = 0; i < 4; ++i) {
            int k = ks * 16 + g * 4 + i;
            if (pre) {
                float v;
                if (k < 64)      v = ldx(A,  (size_t)row * 64 + k, fp32);
                else if (k < 96) v = ldx(Bm, (size_t)row * 32 + (k - 64), fp32);
                else             v = ldx(C,  (size_t)row * 64 + (k - 96), fp32);
                h16 hi = (h16)v;
                outv[i] = (frag < 40) ? hi : (h16)((v - (float)hi) * 2048.f);
            } else if (frag < 96) {
                outv[i] = (h16)ldx(W1, (size_t)row * 64 + k, fp32);
            } else if (frag < 112) {
                outv[i] = (h16)ldx(W2, (size_t)row * 64 + k, fp32);
            } else {
                float v = (k < 64) ? ldx(W3, (size_t)row * 64 + k, fp32)
                                   : ldx(Fm, (size_t)row * 32 + (k - 64), fp32);
                outv[i] = (h16)v;
            }
        }
        ((f16x4*)img)[(size_t)frag * 64 + l] = outv;
    } else if (idx < 8160) {
        int j = idx - 7936;
        float v;
        if      (j < 64)  v = ldx(D,  j,       fp32);
        else if (j < 128) v = ldx(b1, j - 64,  fp32);
        else if (j < 192) v = ldx(b2, j - 128, fp32);
        else              v = ldx(b3, j - 192, fp32) + ldx(G, j - 192, fp32);
        img[15872 + j] = v;
    }
}

// ---------------- CSR build ----------------

__global__ void k_zero_int(int* __restrict__ p, int n) {
    int i = blockIdx.x * blockDim.x + threadIdx.x;
    if (i < n) p[i] = 0;
}

__global__ void k_hist(const int* __restrict__ dst, int* __restrict__ cnt) {
    int e = blockIdx.x * blockDim.x + threadIdx.x;
    if (e < NE_) atomicAdd(&cnt[dst[e]], 1);
}

// parallel scan: chunk=256 exclusive + chunk totals
__global__ void k_scan1(int* __restrict__ cnt, int* __restrict__ partials) {
    __shared__ int sh[256];
    int tid = threadIdx.x;
    int i = blockIdx.x * 256 + tid;
    int v = (i < NN) ? cnt[i] : 0;
    sh[tid] = v;
    __syncthreads();
    for (int off = 1; off < 256; off <<= 1) {
        int a = (tid >= off) ? sh[tid - off] : 0;
        __syncthreads();
        sh[tid] += a;
        __syncthreads();
    }
    if (i < NN) cnt[i] = sh[tid] - v;         // exclusive within chunk
    if (tid == 255) partials[blockIdx.x] = sh[255];
}

__global__ void k_scan2(int* __restrict__ partials, int nchunk) {
    __shared__ int sh[256];
    int tid = threadIdx.x;
    int v = (tid < nchunk) ? partials[tid] : 0;
    sh[tid] = v;
    __syncthreads();
    for (int off = 1; off < 256; off <<= 1) {
        int a = (tid >= off) ? sh[tid - off] : 0;
        __syncthreads();
        sh[tid] += a;
        __syncthreads();
    }
    if (tid < nchunk) partials[tid] = sh[tid] - v;  // exclusive over chunks
}

__global__ void k_scan3(int* __restrict__ cnt, const int* __restrict__ partials) {
    int i = blockIdx.x * 256 + threadIdx.x;
    if (i < NN) cnt[i] += partials[i >> 8];
}

// CSR fill: pairs[pos] = (src node, edge id)
__global__ void k_fill(const int* __restrict__ dst, const int* __restrict__ src,
                       int* __restrict__ cur, int2* __restrict__ pairs) {
    int e = blockIdx.x * blockDim.x + threadIdx.x;
    if (e >= NE_) return;
    int s = src[e];
    int pos = atomicAdd(&cur[dst[e]], 1);
    pairs[pos] = make_int2(s, e);
}

// permute ef into CSR order (f32, exact): efp[b*NE + pos] = ef[b][te][pairs[pos].y]
__global__ void k_perm(const int2* __restrict__ pairs, const void* __restrict__ efeat,
                       int te, const int* __restrict__ flag, float* __restrict__ efp) {
    int fp32 = flag[0];
    for (int i = blockIdx.x * blockDim.x + threadIdx.x; i < 2 * NE_;
         i += gridDim.x * blockDim.x) {
        int b = (i >= NE_) ? 1 : 0;
        int pos = i - b * NE_;
        int eid = pairs[pos].y;
        efp[i] = ldx(efeat, ((size_t)b * NT + te) * NE_ + eid, fp32);
    }
}

// ---------------- state init ----------------
// H layout: node-major, per node 64 dwords = [b0 dims 0..63 | b1 dims 0..63] f16.
__global__ void k_init_H(const void* __restrict__ initH, h16* __restrict__ H,
                         const int* __restrict__ flag) {
    int fp32 = flag[0];
    int i = blockIdx.x * blockDim.x + threadIdx.x;
    if (i < NB * NN * NH_) H[i] = (h16)ldx(initH, i & 63, fp32);
}

// ---------------- aggregation: efp fast path ----------------
// Wave per node; lane l: batch = l>>5, dims 2*(l&31),2*(l&31)+1 (one dword of
// the node's 256B row). pairs/efp reads are wave-uniform (scalar-cache streams);
// only the H gather is vector. 16 independent gathers in flight; next-step ef
// permute fused as grid-stride tail work.
__global__ __launch_bounds__(1024) void k_agg_efp(
    const uint32_t* __restrict__ H2, const int* __restrict__ cend,
    const int2* __restrict__ pairs, const float* __restrict__ efc,
    uint32_t* __restrict__ agg2,
    const void* __restrict__ efeat, int ten, const int* __restrict__ flag,
    float* __restrict__ efn) {
    int n = __builtin_amdgcn_readfirstlane(blockIdx.x * 16 + (threadIdx.x >> 6));
    int lane = threadIdx.x & 63;
    int j0 = (n == 0) ? 0 : cend[n - 1];
    int j1 = cend[n];
    float acc0 = 0.f, acc1 = 0.f;
    int j = j0;
    for (; j + 15 < j1; j += 16) {
        uint32_t h[16]; float ea[16], eb[16];
#pragma unroll
        for (int q = 0; q < 16; ++q) {
            int2 p = pairs[j + q];
            h[q] = H2[(size_t)p.x * 64 + lane];
        }
#pragma unroll
        for (int q = 0; q < 16; ++q) { ea[q] = efc[j + q]; eb[q] = efc[NE_ + j + q]; }
#pragma unroll
        for (int q = 0; q < 16; ++q) {
            float e = (lane < 32) ? ea[q] : eb[q];
            f16x2 v = __builtin_bit_cast(f16x2, h[q]);
            acc0 = fmaf(e, (float)v[0], acc0);
            acc1 = fmaf(e, (float)v[1], acc1);
        }
    }
    for (; j + 3 < j1; j += 4) {
        uint32_t h[4]; float ea[4], eb[4];
#pragma unroll
        for (int q = 0; q < 4; ++q) {
            int2 p = pairs[j + q];
            h[q] = H2[(size_t)p.x * 64 + lane];
        }
#pragma unroll
        for (int q = 0; q < 4; ++q) { ea[q] = efc[j + q]; eb[q] = efc[NE_ + j + q]; }
#pragma unroll
        for (int q = 0; q < 4; ++q) {
            float e = (lane < 32) ? ea[q] : eb[q];
            f16x2 v = __builtin_bit_cast(f16x2, h[q]);
            acc0 = fmaf(e, (float)v[0], acc0);
            acc1 = fmaf(e, (float)v[1], acc1);
        }
    }
    for (; j < j1; ++j) {
        int2 p = pairs[j];
        uint32_t hq = H2[(size_t)p.x * 64 + lane];
        float e = (lane < 32) ? efc[j] : efc[NE_ + j];
        f16x2 v = __builtin_bit_cast(f16x2, hq);
        acc0 = fmaf(e, (float)v[0], acc0);
        acc1 = fmaf(e, (float)v[1], acc1);
    }
    f16x2 o; o[0] = (h16)acc0; o[1] = (h16)acc1;
    agg2[(size_t)n * 64 + lane] = __builtin_bit_cast(uint32_t, o);

    // fused: build next step's permuted ef (off the critical chain, bulk MLP)
    if (ten >= 0) {
        int fp32 = flag[0];
        int gtid = blockIdx.x * 1024 + threadIdx.x;
        for (int i = gtid; i < 2 * NE_; i += gridDim.x * 1024) {
            int b = (i >= NE_) ? 1 : 0;
            int pos = i - b * NE_;
            int eid = pairs[pos].y;
            efn[i] = ldx(efeat, ((size_t)b * NT + ten) * NE_ + eid, fp32);
        }
    }
}

// ---------------- aggregation: legacy path (no efp buffers) ----------------
__global__ __launch_bounds__(256) void k_agg_legacy(
    const uint32_t* __restrict__ H2, const int* __restrict__ cend,
    const int2* __restrict__ pairs, const void* __restrict__ efeat, int te,
    const int* __restrict__ flag, uint32_t* __restrict__ agg2) {
    int n = __builtin_amdgcn_readfirstlane(blockIdx.x * 4 + (threadIdx.x >> 6));
    int lane = threadIdx.x & 63;
    int j0 = (n == 0) ? 0 : cend[n - 1];
    int j1 = cend[n];
    size_t efoff = ((size_t)(lane >> 5) * NT + te) * NE_;
    const float* ef32 = (const float*)efeat + efoff;
    const bf16* ef16 = (const bf16*)efeat + efoff;
    int fp32 = flag[0];
    float acc0 = 0.f, acc1 = 0.f;
    int j = j0;
    for (; j + 7 < j1; j += 8) {
        float e[8]; uint32_t h[8];
#pragma unroll
        for (int q = 0; q < 8; ++q) {
            int2 p = pairs[j + q];
            h[q] = H2[(size_t)p.x * 64 + lane];
            e[q] = fp32 ? ef32[p.y] : b2f(ef16[p.y]);
        }
#pragma unroll
        for (int q = 0; q < 8; ++q) {
            f16x2 v = __builtin_bit_cast(f16x2, h[q]);
            acc0 = fmaf(e[q], (float)v[0], acc0);
            acc1 = fmaf(e[q], (float)v[1], acc1);
        }
    }
    for (; j < j1; ++j) {
        int2 p = pairs[j];
        uint32_t hq = H2[(size_t)p.x * 64 + lane];
        float eq = fp32 ? ef32[p.y] : b2f(ef16[p.y]);
        f16x2 v = __builtin_bit_cast(f16x2, hq);
        acc0 = fmaf(eq, (float)v[0], acc0);
        acc1 = fmaf(eq, (float)v[1], acc1);
    }
    f16x2 o; o[0] = (h16)acc0; o[1] = (h16)acc1;
    agg2[(size_t)n * 64 + lane] = __builtin_bit_cast(uint32_t, o);
}

// ---------------- fused step: pre + tanh + H update + MLP + out ----------------
// One wave = one 16-row M-tile over r = n*2+b. D = W(A-frag) x X^T(B-frag) via
// v_mfma_f32_16x16x16_f16; the x16 shape's D layout equals the B k-layout, so
// each layer's accumulator is directly the next layer's B-fragment.
__global__ __launch_bounds__(512, 4) void k_step(
    const float4* __restrict__ img, const void* __restrict__ x_in,
    void* __restrict__ out, int t, const h16* __restrict__ agg,
    h16* __restrict__ H, const int* __restrict__ flag) {
    __shared__ float4 lds4[4024];  // 64384 B
    int tid = threadIdx.x;
    for (int i = tid; i < 4024; i += 512) lds4[i] = img[i];
    __syncthreads();

    const f16x4* FR = (const f16x4*)lds4;
    const float4* BI = (const float4*)((const float*)lds4 + 15872);
    int lane = tid & 63, m = lane & 15, g = lane >> 4;
    int wid = tid >> 6;
    int fp32v = flag[0];

    int wt = blockIdx.x * 8 + wid;
    if (wt < (NB * NN) / 16) {
        int r = wt * 16 + m;   // interleaved row id (r = n*2 + b)
        int b = r & 1;
        int n = r >> 1;

        const f16x4* Hp = (const f16x4*)(H + (size_t)r * NH_);
        const f16x4* Ap = (const f16x4*)(agg + (size_t)r * NH_);
        f16x4 hf[4], af[4], xf[2];
#pragma unroll
        for (int ks = 0; ks < 4; ++ks) hf[ks] = Hp[ks * 4 + g];
#pragma unroll
        for (int ks = 0; ks < 4; ++ks) af[ks] = Ap[ks * 4 + g];

        size_t xbase = (t < NT) ? (((size_t)b * NT + t) * NN + (size_t)n) * NF
                                : (((size_t)b * (NT + 1) + (NT - 1)) * NN + (size_t)n) * NF;
        const void* xp = (t < NT) ? x_in : (const void*)out;
        if (fp32v) {
            const float4* Xp = (const float4*)((const float*)xp + xbase);
#pragma unroll
            for (int ksl = 0; ksl < 2; ++ksl) {
                float4 xv = Xp[ksl * 4 + g];
                f16x4 h; h[0] = (h16)xv.x; h[1] = (h16)xv.y; h[2] = (h16)xv.z; h[3] = (h16)xv.w;
                xf[ksl] = h;
            }
        } else {
            const ushort4* Xp = (const ushort4*)((const bf16*)xp + xbase);
#pragma unroll
            for (int ksl = 0; ksl < 2; ++ksl) {
                ushort4 xv = Xp[ksl * 4 + g];
                f16x4 h; h[0] = (h16)bu2f(xv.x); h[1] = (h16)bu2f(xv.y);
                h[2] = (h16)bu2f(xv.z); h[3] = (h16)bu2f(xv.w);
                xf[ksl] = h;
            }
        }

        // pre = [H|x|agg] @ [A|Bm|C]^T + D  (hi + lo*2^-11 split weights)
        f32x4 acc[4], accl[4];
#pragma unroll
        for (int ot = 0; ot < 4; ++ot) {
            float4 bv = BI[ot * 4 + g];
            acc[ot]  = f32x4{bv.x, bv.y, bv.z, bv.w};
            accl[ot] = f32x4{0.f, 0.f, 0.f, 0.f};
        }
#pragma unroll
        for (int ks = 0; ks < 10; ++ks) {
            f16x4 bfr = (ks < 4) ? hf[ks] : ((ks < 6) ? xf[ks - 4] : af[ks - 6]);
#pragma unroll
            for (int ot = 0; ot < 4; ++ot) {
                acc[ot] = __builtin_amdgcn_mfma_f32_16x16x16f16(
                    FR[(ot * 10 + ks) * 64 + lane], bfr, acc[ot], 0, 0, 0);
                accl[ot] = __builtin_amdgcn_mfma_f32_16x16x16f16(
                    FR[(40 + ot * 10 + ks) * 64 + lane], bfr, accl[ot], 0, 0, 0);
            }
        }

        // H_new = H + tanh(pre)
        f16x4 hnf[4];
        f16x4* Hw = (f16x4*)(H + (size_t)r * NH_);
#pragma unroll
        for (int ot = 0; ot < 4; ++ot) {
            f16x4 hn;
#pragma unroll
            for (int j = 0; j < 4; ++j) {
                float pre = acc[ot][j] + accl[ot][j] * (1.f / 2048.f);
                hn[j] = (h16)((float)hf[ot][j] + tanhf(pre));
            }
            hnf[ot] = hn;
            Hw[ot * 4 + g] = hn;
        }

        // h1 = relu(Hn @ W1^T + b1)
        f32x4 a1[4];
#pragma unroll
        for (int ot = 0; ot < 4; ++ot) {
            float4 bv = BI[16 + ot * 4 + g];
            a1[ot] = f32x4{bv.x, bv.y, bv.z, bv.w};
        }
#pragma unroll
        for (int ks = 0; ks < 4; ++ks)
#pragma unroll
            for (int ot = 0; ot < 4; ++ot)
                a1[ot] = __builtin_amdgcn_mfma_f32_16x16x16f16(
                    FR[(80 + ot * 4 + ks) * 64 + lane], hnf[ks], a1[ot], 0, 0, 0);
        f16x4 h1f[4];
#pragma unroll
        for (int ot = 0; ot < 4; ++ot) {
            f16x4 h;
#pragma unroll
            for (int j = 0; j < 4; ++j) h[j] = (h16)fmaxf(a1[ot][j], 0.f);
            h1f[ot] = h;
        }

        // h2 = relu(h1 @ W2^T + b2)
        f32x4 a2[4];
#pragma unroll
        for (int ot = 0; ot < 4; ++ot) {
            float4 bv = BI[32 + ot * 4 + g];
            a2[ot] = f32x4{bv.x, bv.y, bv.z, bv.w};
        }
#pragma unroll
        for (int ks = 0; ks < 4; ++ks)
#pragma unroll
            for (int ot = 0; ot < 4; ++ot)
                a2[ot] = __builtin_amdgcn_mfma_f32_16x16x16f16(
                    FR[(96 + ot * 4 + ks) * 64 + lane], h1f[ks], a2[ot], 0, 0, 0);
        f16x4 h2f4[4];
#pragma unroll
        for (int ot = 0; ot < 4; ++ot) {
            f16x4 h;
#pragma unroll
            for (int j = 0; j < 4; ++j) h[j] = (h16)fmaxf(a2[ot][j], 0.f);
            h2f4[ot] = h;
        }

        // y = h2 @ W3^T + x @ Fm^T + (b3 + G)
        f32x4 ay[2];
#pragma unroll
        for (int ot = 0; ot < 2; ++ot) {
            float4 bv = BI[48 + ot * 4 + g];
            ay[ot] = f32x4{bv.x, bv.y, bv.z, bv.w};
        }
#pragma unroll
        for (int ks = 0; ks < 6; ++ks) {
            f16x4 bfr = (ks < 4) ? h2f4[ks] : xf[ks - 4];
#pragma unroll
            for (int ot = 0; ot < 2; ++ot)
                ay[ot] = __builtin_amdgcn_mfma_f32_16x16x16f16(
                    FR[(112 + ot * 6 + ks) * 64 + lane], bfr, ay[ot], 0, 0, 0);
        }

        size_t obase = (((size_t)b * (NT + 1) + t) * NN + (size_t)n) * NF;
        if (fp32v) {
            float4* Op = (float4*)((float*)out + obase);
#pragma unroll
            for (int ot = 0; ot < 2; ++ot)
                Op[ot * 4 + g] = make_float4(ay[ot][0], ay[ot][1], ay[ot][2], ay[ot][3]);
        } else {
            ushort4* Op = (ushort4*)((bf16*)out + obase);
#pragma unroll
            for (int ot = 0; ot < 2; ++ot) {
                ushort4 u;
                u.x = f2bu(ay[ot][0]); u.y = f2bu(ay[ot][1]);
                u.z = f2bu(ay[ot][2]); u.w = f2bu(ay[ot][3]);
                Op[ot * 4 + g] = u;
            }
        }
    }
}

// ---------------- ws-too-small diagnostic ----------------
__global__ void k_diag(float* __restrict__ o, int nwords, float V) {
    int i = blockIdx.x * 256 + threadIdx.x;
    if (i < nwords) o[i] = V;
}

// ---------------- host ----------------

extern "C" void kernel_launch(void* const* d_in, const int* in_sizes, int n_in,
                              void* d_out, int out_size, void* d_ws, size_t ws_size,
                              hipStream_t stream) {
    const void* x_in  = d_in[0];
    const int*  esrc  = (const int*)d_in[1];
    const int*  edst  = (const int*)d_in[2];
    const void* efeat = d_in[3];
    const void* initH = d_in[4];

    const int NCH = (NN + 255) / 256;                  // 196 scan chunks

    // workspace layout
    int*   flag     = (int*)d_ws;                      // 4 ints
    float* img      = (float*)(flag + 4);              // 16096 floats (64384 B)
    int*   cnt      = (int*)(img + 16096);             // NN
    int*   partials = cnt + NN;                        // 256
    int2*  pairs    = (int2*)(partials + 256);         // NE (src, eid)
    h16*   H        = (h16*)(pairs + NE_);             // NB*NN*64
    h16*   agg      = H + (size_t)NB * NN * NH_;       // NB*NN*64
    float* efpA     = (float*)(agg + (size_t)NB * NN * NH_);  // 2*NE f32 (optional)
    float* efpB     = efpA + 2 * NE_;                         // 2*NE f32 (optional)

    size_t base = 16 + 64384 + (size_t)NN * 4 + 1024 + (size_t)NE_ * 8
                + (size_t)NB * NN * NH_ * 2 * 2;
    size_t need_efp = base + (size_t)2 * 2 * NE_ * 4;
    if (ws_size < base) {
        unsigned k = (unsigned)(ws_size >> 20); if (k > 255) k = 255;
        float V = 16.f * (float)(k + 1);
        int nw = out_size / 2;
        k_diag<<<(nw + 255) / 256, 256, 0, stream>>>((float*)d_out, nw, V);
        return;
    }
    int use_efp = (ws_size >= need_efp) ? 1 : 0;

    k_detect<<<1, 256, 0, stream>>>((const uint32_t*)x_in, flag);
    k_fragpack<<<32, 256, 0, stream>>>(
        d_in[5], d_in[6], d_in[7], d_in[8], d_in[9], d_in[10],
        d_in[11], d_in[12], d_in[13], d_in[14], d_in[15], d_in[16], flag, img);
    k_zero_int<<<(NN + 255) / 256, 256, 0, stream>>>(cnt, NN);
    k_hist<<<(NE_ + 255) / 256, 256, 0, stream>>>(edst, cnt);
    k_scan1<<<NCH, 256, 0, stream>>>(cnt, partials);
    k_scan2<<<1, 256, 0, stream>>>(partials, NCH);
    k_scan3<<<NCH, 256, 0, stream>>>(cnt, partials);
    k_fill<<<(NE_ + 255) / 256, 256, 0, stream>>>(edst, esrc, cnt, pairs);
    k_init_H<<<(NB * NN * NH_ + 255) / 256, 256, 0, stream>>>(initH, H, flag);

    int nstep_blocks = ((NB * NN) / 16 + 7) / 8;  // 782

    if (use_efp) {
        k_perm<<<1600, 256, 0, stream>>>(pairs, efeat, 0, flag, efpA);
        float* cur = efpA; float* nxt = efpB;
        for (int t = 0; t < NT + 1; ++t) {
            // te(t+1) differs from te(t) only for t<NT-1; skip dead builds.
            int ten = (t < NT - 1) ? (t + 1) : -1;
            k_agg_efp<<<NN / 16, 1024, 0, stream>>>(
                (const uint32_t*)H, cnt, pairs, cur, (uint32_t*)agg,
                efeat, ten, flag, nxt);
            k_step<<<nstep_blocks, 512, 0, stream>>>(
                (const float4*)img, x_in, d_out, t, agg, H, flag);
            if (ten >= 0) { float* tmp = cur; cur = nxt; nxt = tmp; }
        }
    } else {
        for (int t = 0; t < NT + 1; ++t) {
            int te = (t < NT) ? t : (NT - 1);
            k_agg_legacy<<<NN / 4, 256, 0, stream>>>(
                (const uint32_t*)H, cnt, pairs, efeat, te, flag, (uint32_t*)agg);
            k_step<<<nstep_blocks, 512, 0, stream>>>(
                (const float4*)img, x_in, d_out, t, agg, H, flag);
        }
    }
}